// Round 1
// baseline (867.156 us; speedup 1.0000x reference)
//
#include <hip/hip_runtime.h>
#include <math.h>
#include <float.h>

#define BNS_C 0.9999950000374996f /* 1/sqrt(1+1e-5) */

typedef __bf16 bf8 __attribute__((ext_vector_type(8)));
typedef float f4 __attribute__((ext_vector_type(4)));
union I4BF8 { int4 i; bf8 b; };

static __device__ __forceinline__ unsigned short f2bf(float f) {
    unsigned u = __float_as_uint(f);
    u += 0x7fff + ((u >> 16) & 1);          // round-to-nearest-even
    return (unsigned short)(u >> 16);
}

// ------- x[b][6][1024] -> X0[b][n][8] (zero-padded) + xx norms -------
__global__ void k_xin_t(const float* __restrict__ x, float* __restrict__ X0, float* __restrict__ xx) {
    int i = blockIdx.x * 256 + threadIdx.x;   // over 16384 points
    int b = i >> 10, n = i & 1023;
    const float* xb = x + (((size_t)b * 6) << 10) + n;
    float4* o4 = (float4*)(X0 + ((size_t)i << 3));
    float v0 = xb[0], v1 = xb[1 << 10], v2 = xb[2 << 10];
    float v3 = xb[3 << 10], v4 = xb[4 << 10], v5 = xb[5 << 10];
    o4[0] = make_float4(v0, v1, v2, v3);
    o4[1] = make_float4(v4, v5, 0.f, 0.f);
    xx[i] = v0*v0 + v1*v1 + v2*v2 + v3*v3 + v4*v4 + v5*v5;
}

// ------- w5 f32 [1024][512] -> bf16 [1024][512] (once per launch) -------
__global__ void k_w5b(const float* __restrict__ w5, unsigned short* __restrict__ W5B) {
    int i = blockIdx.x * 256 + threadIdx.x;   // 65536 threads x 8 floats
    const float4* src = (const float4*)(w5 + (size_t)i * 8);
    float4 f0 = src[0], f1 = src[1];
    I4BF8 u_;
    u_.i.x = f2bf(f0.x) | ((unsigned)f2bf(f0.y) << 16);
    u_.i.y = f2bf(f0.z) | ((unsigned)f2bf(f0.w) << 16);
    u_.i.z = f2bf(f1.x) | ((unsigned)f2bf(f1.y) << 16);
    u_.i.w = f2bf(f1.z) | ((unsigned)f2bf(f1.w) << 16);
    *(int4*)(W5B + (size_t)i * 8) = u_.i;
}

// ---- D[z][n][m] = 2*X[n]·X[m] - xx[n] - xx[m]; c-major LDS, b128 frags ----
__global__ __launch_bounds__(256) void k_gram2(const float* __restrict__ X, const float* __restrict__ xx,
                                               float* __restrict__ D, int Cp, int b0) {
    int z = blockIdx.z, b = b0 + z;
    int n0 = blockIdx.y * 64, m0 = blockIdx.x * 64;
    __shared__ float As[32 * 68], Bs[32 * 68];   // [cc][row]
    int tid = threadIdx.x;
    int ti = tid & 15, tj = tid >> 4;
    float acc[4][4] = {};
    const float* Xb = X + (((size_t)b) << 10) * Cp;
    for (int c0 = 0; c0 < Cp; c0 += 32) {
        for (int e = tid; e < 2048; e += 256) {
            int row = e >> 5, cc = e & 31, c = c0 + cc;
            float a = 0.f, bb = 0.f;
            if (c < Cp) {
                a  = Xb[(size_t)(n0 + row) * Cp + c];
                bb = Xb[(size_t)(m0 + row) * Cp + c];
            }
            As[cc * 68 + row] = a; Bs[cc * 68 + row] = bb;
        }
        __syncthreads();
#pragma unroll 8
        for (int cc = 0; cc < 32; ++cc) {
            const float4 av = *(const float4*)(As + cc * 68 + 4 * tj);
            const float4 bv = *(const float4*)(Bs + cc * 68 + 4 * ti);
            acc[0][0] += av.x * bv.x; acc[0][1] += av.x * bv.y; acc[0][2] += av.x * bv.z; acc[0][3] += av.x * bv.w;
            acc[1][0] += av.y * bv.x; acc[1][1] += av.y * bv.y; acc[1][2] += av.y * bv.z; acc[1][3] += av.y * bv.w;
            acc[2][0] += av.z * bv.x; acc[2][1] += av.z * bv.y; acc[2][2] += av.z * bv.z; acc[2][3] += av.z * bv.w;
            acc[3][0] += av.w * bv.x; acc[3][1] += av.w * bv.y; acc[3][2] += av.w * bv.z; acc[3][3] += av.w * bv.w;
        }
        __syncthreads();
    }
    const float4 xm = *(const float4*)(xx + (b << 10) + m0 + 4 * ti);
#pragma unroll
    for (int a = 0; a < 4; ++a) {
        int n = n0 + 4 * tj + a;
        float xn = xx[(b << 10) + n];
        float4 o;
        o.x = 2.f * acc[a][0] - xn - xm.x;
        o.y = 2.f * acc[a][1] - xn - xm.y;
        o.z = 2.f * acc[a][2] - xn - xm.z;
        o.w = 2.f * acc[a][3] - xn - xm.w;
        *(float4*)(D + ((size_t)((z << 10) + n) << 10) + m0 + 4 * ti) = o;
    }
}

// ---- top-20 per row: per-lane Batcher-sorted lists + u64 tournament ----
// key = (sortable(v) << 32) | (1023 - m): one u64 compare == (v desc, m asc). Exact.
#define CE(I,J) { if (kk[I] < kk[J]) { unsigned long long t_ = kk[I]; kk[I] = kk[J]; kk[J] = t_; } }
__global__ __launch_bounds__(256) void k_topk(const float* __restrict__ D, int* __restrict__ idxo, int b0) {
    __shared__ unsigned long long H[4096];       // [wv][16][64] = 32 KB
    int lane = threadIdx.x & 63, wv = threadIdx.x >> 6;
    int rl = blockIdx.x * 4 + wv;
    const float* row = D + ((size_t)rl << 10);
    unsigned long long kk[16];
#pragma unroll
    for (int j = 0; j < 16; ++j) {
        float v = row[lane + 64 * j];
        unsigned u = __float_as_uint(v);
        unsigned s = u ^ ((unsigned)(((int)u) >> 31) | 0x80000000u);
        int m = lane + (j << 6);
        kk[j] = ((unsigned long long)s << 32) | (unsigned)(1023 - m);
    }
    // Batcher odd-even mergesort, 16 inputs, descending (63 CEs)
    CE(0,1) CE(2,3) CE(0,2) CE(1,3) CE(1,2)
    CE(4,5) CE(6,7) CE(4,6) CE(5,7) CE(5,6)
    CE(0,4) CE(2,6) CE(2,4) CE(1,5) CE(3,7) CE(3,5) CE(1,2) CE(3,4) CE(5,6)
    CE(8,9) CE(10,11) CE(8,10) CE(9,11) CE(9,10)
    CE(12,13) CE(14,15) CE(12,14) CE(13,15) CE(13,14)
    CE(8,12) CE(10,14) CE(10,12) CE(9,13) CE(11,15) CE(11,13) CE(9,10) CE(11,12) CE(13,14)
    CE(0,8) CE(4,12) CE(4,8) CE(2,10) CE(6,14) CE(6,10) CE(2,4) CE(6,8) CE(10,12)
    CE(1,9) CE(5,13) CE(5,9) CE(3,11) CE(7,15) CE(7,11) CE(3,5) CE(7,9) CE(11,13)
    CE(1,2) CE(3,4) CE(5,6) CE(7,8) CE(9,10) CE(11,12) CE(13,14)
    // spill sorted list: bank depends only on lane -> conflict-free (2-way)
    unsigned long long* Hw = H + (wv << 10);
#pragma unroll
    for (int j = 0; j < 16; ++j) Hw[(j << 6) + lane] = kk[j];
    int ptr = 0;
    unsigned long long h = kk[0];
    int* outp = idxo + (size_t)((b0 << 10) + rl) * 20;
    for (int it = 0; it < 20; ++it) {
        unsigned long long bk = h;
#pragma unroll
        for (int off = 32; off; off >>= 1) {
            unsigned long long ok = __shfl_down(bk, off);
            if (ok > bk) bk = ok;
        }
        unsigned wlo = __builtin_amdgcn_readfirstlane((unsigned)bk);
        unsigned whi = __builtin_amdgcn_readfirstlane((unsigned)(bk >> 32));
        unsigned long long win = ((unsigned long long)whi << 32) | wlo;
        if (lane == 0) outp[it] = 1023 - (int)(wlo & 1023);
        if (h == win) {
            ++ptr;
            h = (ptr < 16) ? Hw[(ptr << 6) + lane] : 0ULL;
        }
    }
}
#undef CE

// ---- V[b][n][o] = X·Wa^T, U[b][n][o] = X·(Wb-Wa)^T ; c-major LDS, b128 frags ----
__global__ __launch_bounds__(256) void k_uv(const float* __restrict__ X, const float* __restrict__ w,
                                            float* __restrict__ V, float* __restrict__ U,
                                            int Cp, int C, int O) {
    int n0 = blockIdx.x * 64, o0 = blockIdx.y * 64, b = blockIdx.z;
    __shared__ float Xs[32 * 68], Was[32 * 68], Wds[32 * 68];
    int tid = threadIdx.x, ti = tid & 15, tj = tid >> 4;
    float accv[4][4] = {}, accu[4][4] = {};
    const float* Xb = X + (((size_t)b) << 10) * Cp;
    int W2 = 2 * C;
    for (int c0 = 0; c0 < Cp; c0 += 32) {
        for (int e = tid; e < 2048; e += 256) {
            int row = e >> 5, cc = e & 31, c = c0 + cc;
            Xs[cc * 68 + row] = (c < Cp) ? Xb[(size_t)(n0 + row) * Cp + c] : 0.f;
            float wa = 0.f, wd = 0.f;
            if (c < C) {
                float a_ = w[(size_t)(o0 + row) * W2 + c];
                float b_ = w[(size_t)(o0 + row) * W2 + C + c];
                wa = a_; wd = b_ - a_;
            }
            Was[cc * 68 + row] = wa; Wds[cc * 68 + row] = wd;
        }
        __syncthreads();
#pragma unroll 8
        for (int cc = 0; cc < 32; ++cc) {
            const float4 xv = *(const float4*)(Xs  + cc * 68 + 4 * tj);
            const float4 av = *(const float4*)(Was + cc * 68 + 4 * ti);
            const float4 dv = *(const float4*)(Wds + cc * 68 + 4 * ti);
            accv[0][0] += xv.x * av.x; accv[0][1] += xv.x * av.y; accv[0][2] += xv.x * av.z; accv[0][3] += xv.x * av.w;
            accv[1][0] += xv.y * av.x; accv[1][1] += xv.y * av.y; accv[1][2] += xv.y * av.z; accv[1][3] += xv.y * av.w;
            accv[2][0] += xv.z * av.x; accv[2][1] += xv.z * av.y; accv[2][2] += xv.z * av.z; accv[2][3] += xv.z * av.w;
            accv[3][0] += xv.w * av.x; accv[3][1] += xv.w * av.y; accv[3][2] += xv.w * av.z; accv[3][3] += xv.w * av.w;
            accu[0][0] += xv.x * dv.x; accu[0][1] += xv.x * dv.y; accu[0][2] += xv.x * dv.z; accu[0][3] += xv.x * dv.w;
            accu[1][0] += xv.y * dv.x; accu[1][1] += xv.y * dv.y; accu[1][2] += xv.y * dv.z; accu[1][3] += xv.y * dv.w;
            accu[2][0] += xv.z * dv.x; accu[2][1] += xv.z * dv.y; accu[2][2] += xv.z * dv.z; accu[2][3] += xv.z * dv.w;
            accu[3][0] += xv.w * dv.x; accu[3][1] += xv.w * dv.y; accu[3][2] += xv.w * dv.z; accu[3][3] += xv.w * dv.w;
        }
        __syncthreads();
    }
#pragma unroll
    for (int a = 0; a < 4; ++a) {
        int n = n0 + 4 * tj + a;
        size_t base = ((size_t)((b << 10) + n)) * O + o0 + 4 * ti;
        *(float4*)(V + base) = make_float4(accv[a][0], accv[a][1], accv[a][2], accv[a][3]);
        *(float4*)(U + base) = make_float4(accu[a][0], accu[a][1], accu[a][2], accu[a][3]);
    }
}

// ---- out[b][n][o] = max_k leaky(bn(V[m_k]+U[n])); writes f32 Xo, k-sliced bf16 HB, xx ----
__global__ __launch_bounds__(256) void k_gmax(const float* __restrict__ V, const float* __restrict__ U,
                                              const int* __restrict__ idx,
                                              const float* __restrict__ gg, const float* __restrict__ bb,
                                              float* __restrict__ Xo, float* __restrict__ xx,
                                              unsigned short* __restrict__ HB, int coff, int O) {
    __shared__ float sxx[4];
    int tid = threadIdx.x;
    int Tn = 256 / O;
    int j = tid / O, o = tid - j * O;
    int pt = blockIdx.x * Tn + j;          // global point = b*1024+n
    int b = pt >> 10, n = pt & 1023;
    float uv = U[(size_t)pt * O + o];
    float gv = gg[o], bv = bb[o];
    const int* ip = idx + (size_t)pt * 20;
    float mx = -FLT_MAX;
    for (int k = 0; k < 20; ++k) {
        int m = ip[k] & 1023;
        float vv = V[(size_t)((b << 10) + m) * O + o];
        float y = gv * ((vv + uv) * BNS_C) + bv;
        y = y > 0.f ? y : 0.2f * y;
        mx = fmaxf(mx, y);
    }
    Xo[(size_t)pt * O + o] = mx;
    int c = coff + o;
    HB[(((size_t)(b * 16 + (c >> 5)) << 10) + n) * 32 + (c & 31)] = f2bf(mx);
    float s = mx * mx;
#pragma unroll
    for (int off = 32; off; off >>= 1) s += __shfl_down(s, off);
    int wid = tid >> 6, lane = tid & 63;
    if (lane == 0) sxx[wid] = s;
    __syncthreads();
    if (o == 0) {
        int Wpp = O >> 6;
        float t = 0.f;
        for (int w = 0; w < Wpp; ++w) t += sxx[j * Wpp + w];
        xx[pt] = t;
    }
}

// ------- fused MFMA GEMM + BN/leaky + partial max/sum pool, LDS-tiled 128x128 -------
// A = HB (k-sliced bf16, rows = b*1024+n, K=512), B = W5B (bf16 [1024 o][512 c]).
// Block: 256 thr (4 waves, 2x2), tile 128 rows x 128 o, BK=64, 8 K-iters.
// LDS pitch 72 ush = 144 B -> quad = (row + chunk) mod 8 -> 2-way max on b128 r/w (free).
__global__ __launch_bounds__(256) void k_final_mfma(const unsigned short* __restrict__ HB,
                                                    const unsigned short* __restrict__ W5B,
                                                    const float* __restrict__ g5,
                                                    const float* __restrict__ b5,
                                                    float* __restrict__ pp) {
    __shared__ __align__(16) unsigned short As[128 * 72];
    __shared__ __align__(16) unsigned short Bs[128 * 72];
    __shared__ float Lm[2][128], Ls[2][128];
    int rb = blockIdx.x;                     // 0..127 : b = rb>>3, n0 = (rb&7)*128
    int o0 = blockIdx.y << 7;                // 0..896
    int b  = rb >> 3, n0 = (rb & 7) << 7;
    int tid = threadIdx.x, lane = tid & 63, wv = tid >> 6;
    int wm = wv >> 1, wn = wv & 1;
    int ti = lane & 15, tq = lane >> 4;
    int srow = lane >> 3;                    // 0..7 (row within 8-row segment)
    int sch  = lane & 7;                     // chunk 0..7 (8 ush = 16 B each)

    f4 C[4][4];
#pragma unroll
    for (int i = 0; i < 4; ++i)
#pragma unroll
        for (int jj = 0; jj < 4; ++jj) C[i][jj] = (f4){0.f, 0.f, 0.f, 0.f};

    int4 ar[4], br[4];
    // prefetch K-iter 0
    {
#pragma unroll
        for (int j = 0; j < 4; ++j) {
            int rA = (j * 4 + wv) * 8 + srow;                    // 0..127
            ar[j] = *(const int4*)(HB + ((((size_t)(b * 16 + (sch >> 2))) << 10) + n0 + rA) * 32 + (sch & 3) * 8);
            br[j] = *(const int4*)(W5B + (size_t)(o0 + rA) * 512 + sch * 8);
        }
    }
    for (int it = 0; it < 8; ++it) {
        __syncthreads();                      // prev iter's ds_reads done
#pragma unroll
        for (int j = 0; j < 4; ++j) {
            int rA = (j * 4 + wv) * 8 + srow;
            *(int4*)(As + rA * 72 + sch * 8) = ar[j];
            *(int4*)(Bs + rA * 72 + sch * 8) = br[j];
        }
        __syncthreads();                      // tile visible
        if (it < 7) {
            int itn = it + 1, s0 = itn << 1;
#pragma unroll
            for (int j = 0; j < 4; ++j) {
                int rA = (j * 4 + wv) * 8 + srow;
                ar[j] = *(const int4*)(HB + ((((size_t)(b * 16 + s0 + (sch >> 2))) << 10) + n0 + rA) * 32 + (sch & 3) * 8);
                br[j] = *(const int4*)(W5B + (size_t)(o0 + rA) * 512 + itn * 64 + sch * 8);
            }
        }
#pragma unroll
        for (int kk = 0; kk < 2; ++kk) {
            bf8 af[4], bf_[4];
#pragma unroll
            for (int f = 0; f < 4; ++f) {
                int rA = wm * 64 + f * 16 + ti;
                int rB = wn * 64 + f * 16 + ti;
                int ch = kk * 4 + tq;
                I4BF8 ua, ub;
                ua.i = *(const int4*)(As + rA * 72 + ch * 8);
                ub.i = *(const int4*)(Bs + rB * 72 + ch * 8);
                af[f] = ua.b; bf_[f] = ub.b;
            }
#pragma unroll
            for (int fm = 0; fm < 4; ++fm)
#pragma unroll
                for (int fn = 0; fn < 4; ++fn)
                    C[fm][fn] = __builtin_amdgcn_mfma_f32_16x16x32_bf16(af[fm], bf_[fn], C[fm][fn], 0, 0, 0);
        }
    }
    // epilogue: BN + leaky, pool (max,sum) over the 128 rows of this tile
    float gb[4], bvv[4];
#pragma unroll
    for (int f = 0; f < 4; ++f) {
        int o = o0 + wn * 64 + f * 16 + ti;
        gb[f] = g5[o] * BNS_C; bvv[f] = b5[o];
    }
    float mx[4], sm[4];
#pragma unroll
    for (int fn = 0; fn < 4; ++fn) { mx[fn] = -FLT_MAX; sm[fn] = 0.f; }
#pragma unroll
    for (int fm = 0; fm < 4; ++fm)
#pragma unroll
        for (int fn = 0; fn < 4; ++fn)
#pragma unroll
            for (int e = 0; e < 4; ++e) {
                float y = gb[fn] * C[fm][fn][e] + bvv[fn];
                y = y > 0.f ? y : 0.2f * y;
                mx[fn] = fmaxf(mx[fn], y); sm[fn] += y;
            }
#pragma unroll
    for (int fn = 0; fn < 4; ++fn) {
        float m_ = mx[fn], s_ = sm[fn];
        m_ = fmaxf(m_, __shfl_down(m_, 32)); s_ += __shfl_down(s_, 32);
        m_ = fmaxf(m_, __shfl_down(m_, 16)); s_ += __shfl_down(s_, 16);
        if (tq == 0) {
            Lm[wm][wn * 64 + fn * 16 + ti] = m_;
            Ls[wm][wn * 64 + fn * 16 + ti] = s_;
        }
    }
    __syncthreads();
    if (tid < 128) {
        float m_ = fmaxf(Lm[0][tid], Lm[1][tid]);
        float s_ = Ls[0][tid] + Ls[1][tid];
        float* pb = pp + (size_t)rb * 2048;
        pb[o0 + tid] = m_;
        pb[1024 + o0 + tid] = s_;
    }
}

// ---- wl1 FC fused with the row-block partial reduction (8 partials of 128 rows) ----
__global__ __launch_bounds__(256) void k_fc2p(const float* __restrict__ pp, const float* __restrict__ w,
                                              const float* __restrict__ gg, const float* __restrict__ bb,
                                              float* __restrict__ out, int O) {
    int gw = blockIdx.x * 4 + (threadIdx.x >> 6);
    int lane = threadIdx.x & 63;
    int r = gw / O, o = gw - r * O;
    const float* wr = w + (size_t)o * 2048;
    const float* q0 = pp + (size_t)r * 8 * 2048;
    float s = 0.f;
    for (int c = lane; c < 2048; c += 64) {
        float v;
        if (c < 1024) {
            v = q0[c];
#pragma unroll
            for (int t = 1; t < 8; ++t) v = fmaxf(v, q0[t * 2048 + c]);
        } else {
            v = 0.f;
#pragma unroll
            for (int t = 0; t < 8; ++t) v += q0[t * 2048 + c];
            v *= (1.f / 1024.f);
        }
        s += v * wr[c];
    }
#pragma unroll
    for (int off = 32; off; off >>= 1) s += __shfl_down(s, off);
    if (lane == 0) {
        float y = gg[o] * (s * BNS_C) + bb[o];
        out[gw] = y > 0.f ? y : 0.2f * y;
    }
}

// ------- FC tail: one block per batch row, wave-per-output, coalesced weight loads -------
__global__ __launch_bounds__(256) void k_fc_tail(const float* __restrict__ z1,
                                                 const float* __restrict__ wl2, const float* __restrict__ g7, const float* __restrict__ b7,
                                                 const float* __restrict__ wl21,
                                                 const float* __restrict__ wl22, const float* __restrict__ g8, const float* __restrict__ b8,
                                                 const float* __restrict__ wl3,
                                                 float* __restrict__ out) {
    __shared__ float L1[128], L2[64], L3[32];
    int r = blockIdx.x;
    int tid = threadIdx.x, lane = tid & 63, wv = tid >> 6;
    const float* ir = z1 + r * 256;
    float a0 = ir[lane], a1 = ir[lane + 64], a2 = ir[lane + 128], a3 = ir[lane + 192];
    for (int ob = 0; ob < 32; ob += 2) {
        int o0 = wv * 32 + ob, o1 = o0 + 1;
        const float* w0 = wl2 + (size_t)o0 * 256;
        const float* w1 = wl2 + (size_t)o1 * 256;
        float s0 = a0 * w0[lane] + a1 * w0[lane + 64] + a2 * w0[lane + 128] + a3 * w0[lane + 192];
        float s1 = a0 * w1[lane] + a1 * w1[lane + 64] + a2 * w1[lane + 128] + a3 * w1[lane + 192];
#pragma unroll
        for (int off = 32; off; off >>= 1) { s0 += __shfl_down(s0, off); s1 += __shfl_down(s1, off); }
        if (lane == 0) {
            float y0 = g7[o0] * (s0 * BNS_C) + b7[o0]; L1[o0] = y0 > 0.f ? y0 : 0.2f * y0;
            float y1 = g7[o1] * (s1 * BNS_C) + b7[o1]; L1[o1] = y1 > 0.f ? y1 : 0.2f * y1;
        }
    }
    __syncthreads();
    float b0v = L1[lane], b1v = L1[lane + 64];
    for (int ob = 0; ob < 16; ob += 2) {
        int o0 = wv * 16 + ob, o1 = o0 + 1;
        const float* w0 = wl21 + (size_t)o0 * 128;
        const float* w1 = wl21 + (size_t)o1 * 128;
        float s0 = b0v * w0[lane] + b1v * w0[lane + 64];
        float s1 = b0v * w1[lane] + b1v * w1[lane + 64];
#pragma unroll
        for (int off = 32; off; off >>= 1) { s0 += __shfl_down(s0, off); s1 += __shfl_down(s1, off); }
        if (lane == 0) { L2[o0] = s0; L2[o1] = s1; }
    }
    __syncthreads();
    float c0v = L2[lane];
    for (int ob = 0; ob < 8; ob += 2) {
        int o0 = wv * 8 + ob, o1 = o0 + 1;
        float s0 = c0v * wl22[(size_t)o0 * 64 + lane];
        float s1 = c0v * wl22[(size_t)o1 * 64 + lane];
#pragma unroll
        for (int off = 32; off; off >>= 1) { s0 += __shfl_down(s0, off); s1 += __shfl_down(s1, off); }
        if (lane == 0) {
            float y0 = g8[o0] * (s0 * BNS_C) + b8[o0];
            L3[o0] = 0.5f * y0 * (1.f + erff(y0 * 0.70710678118654752f));
            float y1 = g8[o1] * (s1 * BNS_C) + b8[o1];
            L3[o1] = 0.5f * y1 * (1.f + erff(y1 * 0.70710678118654752f));
        }
    }
    __syncthreads();
    float d0v = (lane < 32) ? L3[lane] : 0.f;
    for (int o = wv; o < 90; o += 4) {
        float s = (lane < 32) ? d0v * wl3[(size_t)o * 32 + lane] : 0.f;
#pragma unroll
        for (int off = 32; off; off >>= 1) s += __shfl_down(s, off);
        if (lane == 0) out[r * 90 + o] = s;
    }
}

extern "C" void kernel_launch(void* const* d_in, const int* in_sizes, int n_in,
                              void* d_out, int out_size, void* d_ws, size_t ws_size,
                              hipStream_t stream) {
    typedef const float* fp;
    fp x  = (fp)d_in[0];
    fp w1 = (fp)d_in[2],  g1 = (fp)d_in[3],  b1 = (fp)d_in[4];
    fp w2 = (fp)d_in[5],  g2 = (fp)d_in[6],  b2 = (fp)d_in[7];
    fp w3 = (fp)d_in[8],  g3 = (fp)d_in[9],  b3 = (fp)d_in[10];
    fp w4 = (fp)d_in[11], g4 = (fp)d_in[12], b4 = (fp)d_in[13];
    fp w5 = (fp)d_in[14], g5 = (fp)d_in[15], b5 = (fp)d_in[16];
    fp wl1 = (fp)d_in[17], g6 = (fp)d_in[18], b6 = (fp)d_in[19];
    fp wl2 = (fp)d_in[20], g7 = (fp)d_in[21], b7 = (fp)d_in[22];
    fp wl21 = (fp)d_in[23], wl22 = (fp)d_in[24];
    fp g8 = (fp)d_in[25], b8 = (fp)d_in[26], wl3 = (fp)d_in[27];

    char* ws = (char*)d_ws;
    size_t off = 0;
    auto alloc = [&](size_t floats) { float* p_ = (float*)(ws + off); off += floats * 4; off = (off + 255) & ~(size_t)255; return p_; };
    float* X0  = alloc(131072);       // 16*1024*8
    float* X1  = alloc(1048576);      // [b][n][64]
    float* X2  = alloc(1048576);
    float* X3  = alloc(2097152);      // [b][n][128]
    float* X4  = alloc(4194304);      // [b][n][256]
    float* xx  = alloc(16384);
    int*   nbr = (int*)alloc(327680); // 16*1024*20
    unsigned short* HB = (unsigned short*)alloc(4194304);  // bf16 k-sliced [b][s][n][32]
    unsigned short* W5B = (unsigned short*)alloc(262144);  // bf16 [1024][512]
    float* pp  = alloc(262144);       // 8 row-block partials x 16 b x 2048
    float* z1  = alloc(4096);
    // pool: union of D | V+U
    size_t poolAvail = (ws_size > off) ? (ws_size - off) / 4 : 0;
    int fullD = poolAvail >= 16777216;                 // 64 MB full distance tensor
    float* pool = alloc(fullD ? 16777216 : 8388608);

    float* D = pool;
    float* V = pool;
    float* U = pool + 4194304;

    k_xin_t<<<64, 256, 0, stream>>>(x, X0, xx);
    k_w5b<<<256, 256, 0, stream>>>(w5, W5B);

    struct Blk { const float* Xin; int Cp, C, O, coff; const float *w, *g, *b; float* Xout; };
    Blk blks[4] = {
        {X0, 8,   6,   64,  0,   w1, g1, b1, X1},
        {X1, 64,  64,  64,  64,  w2, g2, b2, X2},
        {X2, 64,  64,  128, 128, w3, g3, b3, X3},
        {X3, 128, 128, 256, 256, w4, g4, b4, X4},
    };
    for (int i = 0; i < 4; ++i) {
        const Blk& B_ = blks[i];
        if (fullD) {
            k_gram2<<<dim3(16, 16, 16), 256, 0, stream>>>(B_.Xin, xx, D, B_.Cp, 0);
            k_topk<<<4096, 256, 0, stream>>>(D, nbr, 0);
        } else {
            for (int b0 = 0; b0 < 16; b0 += 8) {
                k_gram2<<<dim3(16, 16, 8), 256, 0, stream>>>(B_.Xin, xx, D, B_.Cp, b0);
                k_topk<<<2048, 256, 0, stream>>>(D, nbr, b0);
            }
        }
        k_uv<<<dim3(16, B_.O / 64, 16), 256, 0, stream>>>(B_.Xin, B_.w, V, U, B_.Cp, B_.C, B_.O);
        int Tn = 256 / B_.O;
        k_gmax<<<16384 / Tn, 256, 0, stream>>>(V, U, nbr, B_.g, B_.b, B_.Xout, xx, HB, B_.coff, B_.O);
    }

    k_final_mfma<<<dim3(128, 8, 1), 256, 0, stream>>>(HB, W5B, g5, b5, pp);

    k_fc2p<<<(16 * 256) / 4, 256, 0, stream>>>(pp, wl1, g6, b6, z1, 256);
    k_fc_tail<<<16, 256, 0, stream>>>(z1, wl2, g7, b7, wl21, wl22, g8, b8, wl3, (float*)d_out);
}